// Round 3
// baseline (97.208 us; speedup 1.0000x reference)
//
#include <hip/hip_runtime.h>
#include <math.h>

#define LRES 2048
#define NB 8
#define KSEL 64
#define EMBD 16
#define NBIN 128
#define BINSCALE 1.28f           // bin = trunc(d2 * 1.28), d2 < 100 -> bin < 128
#define BINW 0.78125f            // 100/128, upper edge = (T+1)*BINW
#define NSLOT 12                 // selected-push mean 1.05/lane; Poisson P(>=13) ~1e-10

#define LDS_FENCE() asm volatile("s_waitcnt lgkmcnt(0)" ::: "memory")

// one WAVE per row; 4 rows (same batch) per block.
// Batch coordinates staged once per block into LDS (coalesced 24 KB copy);
// pass-1 reads are ds_read_b128 at 48-B lane stride = conflict-free (8 lanes
// cover all 32 banks) with compile-time offset immediates (no address VALU).
__global__ __launch_bounds__(256) void repel_kernel(
    const float* __restrict__ R,
    const int* __restrict__ seq,
    const float* __restrict__ emb,
    const float* __restrict__ wv,
    const float* __restrict__ bias,
    float* __restrict__ partial)
{
    const int w    = threadIdx.x >> 6;
    const int lane = threadIdx.x & 63;
    const int row  = blockIdx.x * 4 + w;
    const int b    = row >> 11;
    const int i    = row & (LRES - 1);

    __shared__ __align__(16) float pts[LRES * 3];   // 24 KB AoS float3 copy
    __shared__ unsigned hist[4][NBIN];              // 2 KB
    __shared__ unsigned slots[4][NSLOT][64];        // 12 KB
    __shared__ unsigned shT[4];
    __shared__ float    shS[4];

    const float* __restrict__ Rb = R + b * (LRES * 3);
    const int*   __restrict__ Sb = seq + b * LRES;

    // ---- stage: coalesced 24 KB copy (6 float4 per thread) ----
    {
        const float4* __restrict__ Rg4 = (const float4*)Rb;
        float4* L4 = (float4*)pts;
#pragma unroll
        for (int k = 0; k < 6; ++k)
            L4[k * 256 + threadIdx.x] = Rg4[k * 256 + threadIdx.x];
    }

    // zero own wave's histogram (2 bins/lane) + default T = NBIN-1
    *(uint2*)&hist[w][lane << 1] = make_uint2(0u, 0u);
    if (lane == 0) shT[w] = NBIN - 1;

    // size-head weights + bias in registers (reused by center and eval)
    const float4 w0 = ((const float4*)wv)[0];
    const float4 w1 = ((const float4*)wv)[1];
    const float4 w2 = ((const float4*)wv)[2];
    const float4 w3 = ((const float4*)wv)[3];
    const float  bias0 = bias[0];

    const float cx = Rb[i * 3 + 0], cy = Rb[i * 3 + 1], cz = Rb[i * 3 + 2];

    float rho_i;
    {
        const float4* e4 = (const float4*)(emb + Sb[i] * EMBD);
        float4 e0 = e4[0], e1 = e4[1], e2 = e4[2], e3 = e4[3];
        float x = bias0;
        x += e0.x * w0.x + e0.y * w0.y + e0.z * w0.z + e0.w * w0.w;
        x += e1.x * w1.x + e1.y * w1.y + e1.z * w1.z + e1.w * w1.w;
        x += e2.x * w2.x + e2.y * w2.y + e2.z * w2.z + e2.w * w2.w;
        x += e3.x * w3.x + e3.y * w3.y + e3.z * w3.z + e3.w * w3.w;
        rho_i = 1.6f + 1.2f / (1.0f + __expf(-x));
    }

    // blocks of 256 j's that can contain excluded pairs |i-j|<=2 (wave-uniform)
    const int tlo = ((i - 2 > 0) ? (i - 2) : 0) >> 8;
    const int thi = ((i + 2 < LRES - 1) ? (i + 2) : (LRES - 1)) >> 8;

    __syncthreads();   // staging + hist zero-init complete

    // ---- pass 1: lane owns 32 j's (8 iters x 4 points, 3 ds_read_b128 each) ----
    const char* lp = (const char*)pts + lane * 48;   // lane's base; offsets are immediates
    unsigned d2u[32];
#pragma unroll
    for (int t = 0; t < 8; ++t) {
        float4 u0 = *(const float4*)(lp + t * 3072);
        float4 u1 = *(const float4*)(lp + t * 3072 + 16);
        float4 u2 = *(const float4*)(lp + t * 3072 + 32);
        const int  jb = (t << 8) + (lane << 2);
        const bool ex = (t == tlo) || (t == thi);
        float px[4] = {u0.x, u0.w, u1.z, u2.y};
        float py[4] = {u0.y, u1.x, u1.w, u2.z};
        float pz[4] = {u0.z, u1.y, u2.x, u2.w};
#pragma unroll
        for (int q = 0; q < 4; ++q) {
            float dx = px[q] - cx, dy = py[q] - cy, dz = pz[q] - cz;
            float d2 = dx * dx + dy * dy + dz * dz;
            unsigned du = __float_as_uint(d2);
            if (ex) {                              // only 1-2 of 8 iterations
                int dij = jb + q - i; dij = (dij < 0) ? -dij : dij;
                if (dij <= 2) du = 0xFFFFFFFFu;
            }
            d2u[t * 4 + q] = du;
            if (du <= 0x42C7FFFFu)                 // d2 < 100.0
                atomicAdd(&hist[w][(unsigned)(d2 * BINSCALE)], 1u);
        }
    }
    LDS_FENCE();

    // ---- scan: lane holds 2 bins; 64-lane inclusive scan; crossing lane sets T ----
    uint2 hv = *(const uint2*)&hist[w][lane << 1];
    unsigned p = hv.x + hv.y;
    unsigned s = p;
#pragma unroll
    for (int o = 1; o < 64; o <<= 1) {
        unsigned uu = __shfl_up(s, o, 64);
        if (lane >= o) s += uu;
    }
    unsigned e0s = s - p;
    if (s >= KSEL && e0s < KSEL) {                 // unique crossing lane (if total >= 64)
        unsigned sub = (e0s + hv.x >= KSEL) ? 0u : 1u;
        shT[w] = (lane << 1) + sub;                // whole boundary bin selected
    }
    LDS_FENCE();
    const unsigned T   = shT[w];                   // wave-uniform broadcast read
    const unsigned tkb = __float_as_uint((float)(T + 1) * BINW);

    // ---- capture: each lane writes its selected (d2|j) to private slots ----
    unsigned cnt = 0;
#pragma unroll
    for (int m = 0; m < 32; ++m) {
        if (d2u[m] < tkb && cnt < NSLOT) {
            unsigned j = (unsigned)(((m >> 2) << 8) + (m & 3)) + ((unsigned)lane << 2);
            slots[w][cnt][lane] = (d2u[m] & 0xFFFFF800u) | j;   // j < 2048 in low 11 bits
            ++cnt;
        }
    }
    LDS_FENCE();

    // ---- eval own slots (~1-2 iterations) with on-the-fly rho_j ----
    float acc = 0.0f;
    for (unsigned k = 0; k < cnt; ++k) {
        unsigned key = slots[w][k][lane];
        unsigned j   = key & 2047u;
        float d2 = __uint_as_float(key & 0xFFFFF800u);
        float r  = __fsqrt_rn(fmaxf(d2, 1e-12f));
        const float4* e4 = (const float4*)(emb + Sb[j] * EMBD);
        float4 e0 = e4[0], e1 = e4[1], e2 = e4[2], e3 = e4[3];
        float x = bias0;
        x += e0.x * w0.x + e0.y * w0.y + e0.z * w0.z + e0.w * w0.w;
        x += e1.x * w1.x + e1.y * w1.y + e1.z * w1.z + e1.w * w1.w;
        x += e2.x * w2.x + e2.y * w2.y + e2.z * w2.z + e2.w * w2.w;
        x += e3.x * w3.x + e3.y * w3.y + e3.z * w3.z + e3.w * w3.w;
        float rho_j = 1.6f + 1.2f / (1.0f + __expf(-x));
        float xx = (rho_i + rho_j - r) * (1.0f / 0.3f);
        float sp = fmaxf(xx, 0.0f) + __logf(1.0f + __expf(-fabsf(xx)));
        float tt = fminf(fmaxf((r - 8.0f) * 0.5f, 0.0f), 1.0f);
        float sw = 1.0f - tt * tt * (3.0f - 2.0f * tt);
        acc += 10.0f * sp * sw;
    }

    // ---- wave reduce -> block reduce -> ONE plain store per block ----
#pragma unroll
    for (int o = 32; o > 0; o >>= 1) acc += __shfl_down(acc, o, 64);
    if (lane == 0) shS[w] = acc;
    __syncthreads();
    if (threadIdx.x == 0)
        partial[blockIdx.x] = shS[0] + shS[1] + shS[2] + shS[3];
}

// out[b] = sum of 512 per-block partials (blocks 512b .. 512b+511)
__global__ void reduce_kernel(const float* __restrict__ partial, float* __restrict__ out) {
    __shared__ float sh[4];
    const int b = blockIdx.x;
    const int tid = threadIdx.x;
    float acc = partial[(b << 9) + tid] + partial[(b << 9) + 256 + tid];
#pragma unroll
    for (int o = 32; o > 0; o >>= 1) acc += __shfl_down(acc, o, 64);
    if ((tid & 63) == 0) sh[tid >> 6] = acc;
    __syncthreads();
    if (tid == 0) out[b] = sh[0] + sh[1] + sh[2] + sh[3];
}

extern "C" void kernel_launch(void* const* d_in, const int* in_sizes, int n_in,
                              void* d_out, int out_size, void* d_ws, size_t ws_size,
                              hipStream_t stream) {
    const float* R    = (const float*)d_in[0];   // (8, 2048, 3) f32
    const int*   seq  = (const int*)d_in[1];     // (8, 2048) int
    const float* emb  = (const float*)d_in[2];   // (20, 16) f32
    const float* w    = (const float*)d_in[3];   // (1, 16) f32
    const float* bias = (const float*)d_in[4];   // (1,) f32
    float* out = (float*)d_out;                  // (8,) f32

    float* partial = (float*)d_ws;               // 16 KB (4096 block partials)

    repel_kernel<<<NB * LRES / 4, 256, 0, stream>>>(R, seq, emb, w, bias, partial);
    reduce_kernel<<<NB, 256, 0, stream>>>(partial, out);
}

// Round 4
// 88.579 us; speedup vs baseline: 1.0974x; 1.0974x over previous
//
#include <hip/hip_runtime.h>
#include <hip/hip_fp16.h>
#include <math.h>

#define LRES 2048
#define NB 8
#define KSEL 64
#define EMBD 16
#define NBIN 128
#define BINSCALE 1.28f          // bin = trunc(d2 * 1.28), d2 < 100 -> bin < 128
#define BINW 0.78125f           // 100/128, upper edge = (T+1)*BINW
#define NSLOT 16                // per-lane slot cap (Poisson(1) tail: P(>16) ~ 1e-14)

// prep: per-residue rho + pack (x,y,z,rho) as half4 into ws
__global__ void prep_kernel(const float* __restrict__ R,
                            const int* __restrict__ seq,
                            const float* __restrict__ emb,
                            const float* __restrict__ w,
                            const float* __restrict__ bias,
                            uint2* __restrict__ pts) {
    int idx = blockIdx.x * blockDim.x + threadIdx.x;
    if (idx < NB * LRES) {
        int s = seq[idx];
        float x = bias[0];
#pragma unroll
        for (int d = 0; d < EMBD; ++d) x += emb[s * EMBD + d] * w[d];
        float rho = 1.6f + 1.2f / (1.0f + expf(-x));
        __half2 h0 = __floats2half2_rn(R[idx * 3 + 0], R[idx * 3 + 1]);
        __half2 h1 = __floats2half2_rn(R[idx * 3 + 2], rho);
        pts[idx] = make_uint2(*(unsigned*)&h0, *(unsigned*)&h1);
    }
}

#define LDS_FENCE() asm volatile("s_waitcnt lgkmcnt(0)" ::: "memory")

// one WAVE per row; 4 independent waves per block; no __syncthreads until the
// final block-combine. Round-0 structure (fp16-packed global loads, 8 blocks/CU)
// + scalar-hoisted exclusion check + branchless capture.
__global__ __launch_bounds__(256, 8) void repel_kernel(const uint2* __restrict__ pts,
                                                       float* __restrict__ partial) {
    const int w    = threadIdx.x >> 6;
    const int lane = threadIdx.x & 63;
    const int row  = blockIdx.x * 4 + w;
    const int b    = row >> 11;
    const int i    = row & (LRES - 1);

    __shared__ unsigned hist[4][NBIN];            // 2 KB
    __shared__ unsigned slots[4][NSLOT][64];      // 16 KB; bank = lane&31: 2-way (free)
    __shared__ unsigned shT[4];
    __shared__ float    shS[4];

    const uint2* __restrict__ P  = pts + (b << 11);
    const uint4* __restrict__ P4 = (const uint4*)P;

    // zero own wave's histogram (2 bins/lane) + default T = NBIN-1 (select all in-cutoff)
    *(uint2*)&hist[w][lane << 1] = make_uint2(0u, 0u);
    if (lane == 0) shT[w] = NBIN - 1;

    float2 cc0 = __half22float2(*(__half2*)&P[i].x);
    float2 cc1 = __half22float2(*(__half2*)&P[i].y);
    const float cx = cc0.x, cy = cc0.y, cz = cc1.x, rho_i = cc1.y;

    // scalar exclusion window: i is wave-uniform -> SGPR; t covers 128 j's
    const int s_i = __builtin_amdgcn_readfirstlane(i);
    const int tlo = ((s_i - 2 > 0) ? (s_i - 2) : 0) >> 7;
    const int thi = ((s_i + 2 < LRES - 1) ? (s_i + 2) : (LRES - 1)) >> 7;

    const unsigned lane2 = (unsigned)lane << 1;
    LDS_FENCE();   // zero-init complete before atomics

    // ---- pass 1: distances (lane owns 32 j's) + fused per-wave histogram ----
    unsigned d2u[32];
#pragma unroll
    for (int t = 0; t < 16; ++t) {
        uint4 u = P4[(t << 6) + lane];               // points j0, j0+1
        int j0 = (t << 7) + (int)lane2;
        float2 f0 = __half22float2(*(__half2*)&u.x);
        float2 f1 = __half22float2(*(__half2*)&u.y);
        float dx0 = f0.x - cx, dy0 = f0.y - cy, dz0 = f1.x - cz;
        float d2a = dx0 * dx0 + dy0 * dy0 + dz0 * dz0;
        float2 g0 = __half22float2(*(__half2*)&u.z);
        float2 g1 = __half22float2(*(__half2*)&u.w);
        float dx1 = g0.x - cx, dy1 = g0.y - cy, dz1 = g1.x - cz;
        float d2b = dx1 * dx1 + dy1 * dy1 + dz1 * dz1;
        unsigned dua = __float_as_uint(d2a);
        unsigned dub = __float_as_uint(d2b);
        if (t == tlo || t == thi) {                  // scalar compare: uniform branch
            int e0 = j0 - i;     e0 = (e0 < 0) ? -e0 : e0;
            int e1 = j0 + 1 - i; e1 = (e1 < 0) ? -e1 : e1;
            if (e0 <= 2) dua = 0xFFFFFFFFu;
            if (e1 <= 2) dub = 0xFFFFFFFFu;
        }
        d2u[2 * t]     = dua;
        d2u[2 * t + 1] = dub;
        if (dua <= 0x42C7FFFFu)                      // d2 < 100.0
            atomicAdd(&hist[w][(unsigned)(d2a * BINSCALE)], 1u);
        if (dub <= 0x42C7FFFFu)
            atomicAdd(&hist[w][(unsigned)(d2b * BINSCALE)], 1u);
    }
    LDS_FENCE();

    // ---- scan: lane holds 2 bins; 64-lane inclusive scan; crossing lane sets T ----
    uint2 hv = *(const uint2*)&hist[w][lane << 1];
    unsigned p = hv.x + hv.y;
    unsigned s = p;
#pragma unroll
    for (int o = 1; o < 64; o <<= 1) {
        unsigned uu = __shfl_up(s, o, 64);
        if (lane >= o) s += uu;
    }
    unsigned e0s = s - p;
    if (s >= KSEL && e0s < KSEL) {                   // unique crossing lane (if total >= 64)
        unsigned sub = (e0s + hv.x >= KSEL) ? 0u : 1u;
        shT[w] = (lane << 1) + sub;                  // whole boundary bin selected
    }
    LDS_FENCE();
    const unsigned T   = shT[w];                     // wave-uniform broadcast read
    const unsigned tkb = __float_as_uint((float)(T + 1) * BINW);

    // ---- capture: branchless; garbage writes at slot[cnt] are overwritten or unread ----
    unsigned cnt = 0;
#pragma unroll
    for (int m = 0; m < 32; ++m) {
        const unsigned jm  = (unsigned)(((m >> 1) << 7) | (m & 1));   // const per m
        unsigned val  = (d2u[m] & 0xFFFFF800u) | jm | lane2;          // j bits disjoint
        unsigned sel  = (d2u[m] < tkb) ? 1u : 0u;
        unsigned widx = (cnt > NSLOT - 1) ? (NSLOT - 1) : cnt;
        slots[w][widx][lane] = val;
        cnt += sel;
    }
    LDS_FENCE();

    // ---- eval own slots (wave runs max-cnt ~4 iterations) + wave reduce ----
    float acc = 0.0f;
    for (unsigned k = 0; k < cnt; ++k) {
        unsigned key = slots[w][k][lane];
        unsigned j = key & 2047u;
        float d2 = __uint_as_float(key & 0xFFFFF800u);
        float r = __fsqrt_rn(fmaxf(d2, 1e-12f));
        uint2 pj = P[j];
        float rho_j = __high2float(*(__half2*)&pj.y);
        float x = (rho_i + rho_j - r) * (1.0f / 0.3f);
        float sp = fmaxf(x, 0.0f) + __logf(1.0f + __expf(-fabsf(x)));
        float t = fminf(fmaxf((r - 8.0f) * 0.5f, 0.0f), 1.0f);
        float sw = 1.0f - t * t * (3.0f - 2.0f * t);
        acc += 10.0f * sp * sw;
    }
#pragma unroll
    for (int o = 32; o > 0; o >>= 1) acc += __shfl_down(acc, o, 64);

    // ---- block combine -> ONE plain store per block ----
    if (lane == 0) shS[w] = acc;
    __syncthreads();
    if (threadIdx.x == 0)
        partial[blockIdx.x] = shS[0] + shS[1] + shS[2] + shS[3];
}

// out[b] = sum of 512 per-block partials (blocks 512b .. 512b+511)
__global__ void reduce_kernel(const float* __restrict__ partial, float* __restrict__ out) {
    __shared__ float sh[4];
    const int b = blockIdx.x;
    const int tid = threadIdx.x;
    float acc = partial[(b << 9) + tid] + partial[(b << 9) + 256 + tid];
#pragma unroll
    for (int o = 32; o > 0; o >>= 1) acc += __shfl_down(acc, o, 64);
    if ((tid & 63) == 0) sh[tid >> 6] = acc;
    __syncthreads();
    if (tid == 0) out[b] = sh[0] + sh[1] + sh[2] + sh[3];
}

extern "C" void kernel_launch(void* const* d_in, const int* in_sizes, int n_in,
                              void* d_out, int out_size, void* d_ws, size_t ws_size,
                              hipStream_t stream) {
    const float* R    = (const float*)d_in[0];   // (8, 2048, 3) f32
    const int*   seq  = (const int*)d_in[1];     // (8, 2048) int
    const float* emb  = (const float*)d_in[2];   // (20, 16) f32
    const float* w    = (const float*)d_in[3];   // (1, 16) f32
    const float* bias = (const float*)d_in[4];   // (1,) f32
    float* out = (float*)d_out;                  // (8,) f32

    uint2* pts     = (uint2*)d_ws;                                       // 128 KB
    float* partial = (float*)((char*)d_ws + NB * LRES * sizeof(uint2));  // 16 KB

    prep_kernel<<<(NB * LRES + 255) / 256, 256, 0, stream>>>(R, seq, emb, w, bias, pts);
    repel_kernel<<<NB * LRES / 4, 256, 0, stream>>>(pts, partial);
    reduce_kernel<<<NB, 256, 0, stream>>>(partial, out);
}